// Round 4
// baseline (492.823 us; speedup 1.0000x reference)
//
#include <hip/hip_runtime.h>
#include <hip/hip_bf16.h>
#include <math.h>

#define NB 4096      // tokens
#define ND 1024      // model dim
#define NH 4096      // hidden dim
#define NE 8         // experts
#define NKK 2        // top-k
#define NROWS (NB*NKK)   // 8192 (token,slot) rows
#define MAXT2 40         // max 256-row tiles: 32 full + 8 partial (4 groups of 10)

typedef __attribute__((ext_vector_type(8))) short short8;
typedef __attribute__((ext_vector_type(4))) float f32x4;

__device__ __forceinline__ void gload_lds16(const void* g, void* l) {
    __builtin_amdgcn_global_load_lds(
        (const __attribute__((address_space(1))) unsigned int*)g,
        (__attribute__((address_space(3))) unsigned int*)l, 16, 0, 0);
}

__device__ __forceinline__ unsigned short f2bf(float f) {
    __hip_bfloat16 h = __float2bfloat16(f);
    return *reinterpret_cast<unsigned short*>(&h);
}

// exact-gelu via A&S 7.1.26 erf approx (|erf err| < 1.5e-7), hw exp/rcp
__device__ __forceinline__ float fast_gelu(float x) {
    float xs  = x * 0.70710678118654752f;
    float axs = fabsf(xs);
    float t   = __builtin_amdgcn_rcpf(1.0f + 0.3275911f * axs);
    float p   = t * (0.254829592f + t * (-0.284496736f + t * (1.421413741f +
                t * (-1.453152027f + t * 1.061405429f))));
    float e   = __expf(-xs * xs);
    float erf_abs = 1.0f - p * e;
    float erf = copysignf(erf_abs, x);
    return 0.5f * x * (1.0f + erf);
}

// ---------------- prep kernels ----------------

// in: [E][R][C] f32  ->  out: [E][C][R] bf16  (transpose + convert)
__global__ void k_transpose_cvt(const float* __restrict__ in, __hip_bfloat16* __restrict__ out,
                                int R, int C) {
    __shared__ float tile[64][68];
    const size_t ebase = (size_t)blockIdx.z * R * C;
    const int r0 = blockIdx.y * 64, c0 = blockIdx.x * 64;
    const int t = threadIdx.x;
    const int lr = t >> 4, lc4 = (t & 15) * 4;
    #pragma unroll
    for (int i = 0; i < 4; ++i) {
        int r = lr + i * 16;
        float4 v = *reinterpret_cast<const float4*>(&in[ebase + (size_t)(r0 + r) * C + (c0 + lc4)]);
        *reinterpret_cast<float4*>(&tile[r][lc4]) = v;
    }
    __syncthreads();
    const int q = t & 15, cw = t >> 4;
    #pragma unroll
    for (int i = 0; i < 4; ++i) {
        int cc = cw + i * 16;
        ushort4 v;
        v.x = f2bf(tile[q*4+0][cc]);
        v.y = f2bf(tile[q*4+1][cc]);
        v.z = f2bf(tile[q*4+2][cc]);
        v.w = f2bf(tile[q*4+3][cc]);
        *reinterpret_cast<ushort4*>(&out[ebase + (size_t)(c0 + cc) * R + (r0 + q*4)]) = v;
    }
}

// ---------------- routing ----------------

__global__ void k_route_count(const int* __restrict__ idx, int* cnt) {
    int b = blockIdx.x * 256 + threadIdx.x;
    if (b < NB) {
        atomicAdd(&cnt[idx[2*b]], 1);
        atomicAdd(&cnt[idx[2*b+1]], 1);
    }
}

// prefix offsets + expert-pure 256-row tile list
__global__ void k_route_scan(const int* __restrict__ cnt, int* offs, int* cursor,
                             int* tile_e, int* tile_row, int* ntiles) {
    if (threadIdx.x == 0) {
        int s = 0, t = 0;
        for (int e = 0; e < NE; ++e) {
            offs[e] = s; cursor[e] = s;
            for (int r = 0; r < cnt[e]; r += 256) {
                tile_e[t] = e; tile_row[t] = s + r; ++t;
            }
            s += cnt[e];
        }
        offs[NE] = s;
        *ntiles = t;
    }
}

__global__ void k_route_fill(const int* __restrict__ idx, const float* __restrict__ hw,
                             int* cursor, int* tok, float* gw) {
    int b = blockIdx.x * 256 + threadIdx.x;
    if (b < NB) {
        #pragma unroll
        for (int k = 0; k < NKK; ++k) {
            int e = idx[2*b + k];
            int p = atomicAdd(&cursor[e], 1);
            tok[p] = b;
            gw[p]  = hw[2*b + k];
        }
    }
}

// gather + f32->bf16: Ag[row] = bf16(x[tok[row]])   (one block per row)
__global__ void k_gather_cvt(const float* __restrict__ x, const int* __restrict__ tok,
                             __hip_bfloat16* __restrict__ Ag) {
    const int row = blockIdx.x;
    const float4 v = reinterpret_cast<const float4*>(x + (size_t)tok[row] * ND)[threadIdx.x];
    ushort4 u; u.x = f2bf(v.x); u.y = f2bf(v.y); u.z = f2bf(v.z); u.w = f2bf(v.w);
    reinterpret_cast<ushort4*>(Ag + (size_t)row * ND)[threadIdx.x] = u;
}

// ------- grouped GEMM: 256-row tile, 8 waves, BK=64, double-buffered LDS -------
// STAGE 1: h = gelu(Ag @ w1t^T + b1)          BM=256 BN=256, K=1024
// STAGE 2: out += gw*(h @ w2t^T + b2)         BM=256 BN=128, K=4096 split 2
// 2-phase pipeline: STAGE(next buf) issued BEFORE compute(cur buf); one
// __syncthreads per K-tile (drains vmcnt+lgkmcnt, publishes LDS).

template<int STAGE>
__global__ __launch_bounds__(512, 2) void moe_gemm(
    const __hip_bfloat16* __restrict__ Asrc,   // Ag (st1) or h (st2), contiguous rows
    const __hip_bfloat16* __restrict__ Bt,     // [E][N][K] bf16
    const float* __restrict__ bias,            // [E][N]
    __hip_bfloat16* __restrict__ Hout,
    float* __restrict__ Out,
    const int* __restrict__ offs,
    const int* __restrict__ tok,
    const float* __restrict__ gw,
    const int* __restrict__ tile_e,
    const int* __restrict__ tile_row,
    const int* __restrict__ ntiles)
{
    constexpr int N   = (STAGE == 1) ? NH : ND;
    constexpr int K   = (STAGE == 1) ? ND : NH;     // full K (row stride)
    constexpr int BN  = (STAGE == 1) ? 256 : 128;
    constexpr int KT  = (STAGE == 1) ? 16 : 32;     // K-tiles of 64 per block
    constexpr int NI  = BN / 64;                    // N frags per wave: 4 / 2
    constexpr int BR  = (BN * 64) / (512 * 8);      // B staging rounds: 4 / 2
    constexpr int ASZ = 256 * 64;                   // bf16 units per A buffer
    constexpr int BUF = ASZ + BN * 64;

    extern __shared__ __hip_bfloat16 smem[];        // 2 * BUF

    // 2D XCD partition: stage1 (tilegrp x N-half), stage2 (tilegrp x K-half)
    const int bid = blockIdx.x;
    const int xcd = bid & 7;
    const int c   = bid >> 3;          // 0..79
    const int tile = (xcd >> 1) * 10 + (c >> 3);
    const int sub  = c & 7;
    if (tile >= *ntiles) return;

    int nt, kbase;
    if (STAGE == 1) { nt = (xcd & 1) * 8 + sub; kbase = 0; }
    else            { nt = sub;                 kbase = (xcd & 1) * (NH / 2); }

    const int e = tile_e[tile];
    const int rowbase = tile_row[tile];
    const int end = offs[e + 1];

    const int tid = threadIdx.x;
    const int w = tid >> 6, l = tid & 63;
    const int srow = tid >> 3;                    // 0..63
    const int schunk = (tid & 7) ^ (srow & 7);    // source-side XOR swizzle

    const __hip_bfloat16* aptr[4];
    #pragma unroll
    for (int r = 0; r < 4; ++r) {
        int re = rowbase + srow + r * 64; if (re > end - 1) re = end - 1;
        aptr[r] = Asrc + (size_t)re * K + kbase + schunk * 8;
    }
    const __hip_bfloat16* bptr[BR];
    #pragma unroll
    for (int r = 0; r < BR; ++r)
        bptr[r] = Bt + ((size_t)e * N + (size_t)(nt * BN + srow + r * 64)) * K + kbase + schunk * 8;

    const int wm  = (w >> 2) * 128;
    const int wn  = (w & 3) * (BN / 4);
    const int l15 = l & 15, l4 = l >> 4;

    // row&7 == l15&7 for all frag rows -> swizzled 16B-chunk bytes, 2 values
    const int cs[2] = { ((l4) ^ (l15 & 7)) * 16, ((4 + l4) ^ (l15 & 7)) * 16 };
    const int abase = (wm + l15) * 128;
    const int bbase = (wn + l15) * 128;

    f32x4 acc[8][NI];
    #pragma unroll
    for (int mi = 0; mi < 8; ++mi)
        #pragma unroll
        for (int ni = 0; ni < NI; ++ni) acc[mi][ni] = (f32x4){0.f, 0.f, 0.f, 0.f};

    auto stage_t = [&](int b, int kt) {
        __hip_bfloat16* da = smem + b * BUF;
        __hip_bfloat16* db = da + ASZ;
        #pragma unroll
        for (int r = 0; r < 4; ++r)  gload_lds16(aptr[r] + kt * 64, da + tid * 8 + r * 4096);
        #pragma unroll
        for (int r = 0; r < BR; ++r) gload_lds16(bptr[r] + kt * 64, db + tid * 8 + r * 4096);
    };

    stage_t(0, 0);
    __syncthreads();

    int cur = 0;
    #pragma unroll 1
    for (int kt = 0; kt < KT; ++kt) {
        if (kt + 1 < KT) stage_t(cur ^ 1, kt + 1);   // issue next tile EARLY
        const char* sa = (const char*)(smem + cur * BUF);
        const char* sb = (const char*)(smem + cur * BUF + ASZ);
        __builtin_amdgcn_s_setprio(1);
        #pragma unroll
        for (int ks = 0; ks < 2; ++ks) {
            short8 af[8], bfv[NI];
            #pragma unroll
            for (int mi = 0; mi < 8; ++mi)
                af[mi] = *(const short8*)(sa + abase + mi * 2048 + cs[ks]);
            #pragma unroll
            for (int ni = 0; ni < NI; ++ni)
                bfv[ni] = *(const short8*)(sb + bbase + ni * 2048 + cs[ks]);
            #pragma unroll
            for (int mi = 0; mi < 8; ++mi)
                #pragma unroll
                for (int ni = 0; ni < NI; ++ni)
                    acc[mi][ni] = __builtin_amdgcn_mfma_f32_16x16x32_bf16(
                        af[mi], bfv[ni], acc[mi][ni], 0, 0, 0);
        }
        __builtin_amdgcn_s_setprio(0);
        __syncthreads();                             // drains vmcnt; publishes LDS
        cur ^= 1;
    }

    // epilogue --- C/D frag layout: col = l&15, row = (l>>4)*4 + j  [m89]
    const int ncol0 = nt * BN + wn;
    #pragma unroll
    for (int mi = 0; mi < 8; ++mi) {
        #pragma unroll
        for (int ni = 0; ni < NI; ++ni) {
            const int gn = ncol0 + ni * 16 + l15;
            const float bv = bias[e * N + gn];
            #pragma unroll
            for (int j = 0; j < 4; ++j) {
                const int re = rowbase + wm + mi * 16 + l4 * 4 + j;
                if (re < end) {
                    float v = acc[mi][ni][j];
                    if (STAGE == 1) {
                        v += bv;
                        Hout[(size_t)re * NH + gn] = __float2bfloat16(fast_gelu(v));
                    } else {
                        if (kbase == 0) v += bv;
                        atomicAdd(&Out[(size_t)tok[re] * ND + gn], gw[re] * v);
                    }
                }
            }
        }
    }
}

// ---------------- launch ----------------

extern "C" void kernel_launch(void* const* d_in, const int* in_sizes, int n_in,
                              void* d_out, int out_size, void* d_ws, size_t ws_size,
                              hipStream_t stream) {
    const float* x   = (const float*)d_in[0];
    const int*   idx = (const int*)d_in[1];
    const float* hw  = (const float*)d_in[2];
    const float* w1  = (const float*)d_in[3];
    const float* b1  = (const float*)d_in[4];
    const float* w2  = (const float*)d_in[5];
    const float* b2  = (const float*)d_in[6];
    float* out = (float*)d_out;

    char* ws = (char*)d_ws;
    size_t off = 0;
    __hip_bfloat16* Ag  = (__hip_bfloat16*)(ws + off); off += (size_t)NROWS * ND * 2;
    __hip_bfloat16* w1t = (__hip_bfloat16*)(ws + off); off += (size_t)NE * ND * NH * 2;
    __hip_bfloat16* w2t = (__hip_bfloat16*)(ws + off); off += (size_t)NE * NH * ND * 2;
    __hip_bfloat16* h   = (__hip_bfloat16*)(ws + off); off += (size_t)NROWS * NH * 2;
    int*   tok     = (int*)(ws + off);   off += NROWS * 4;
    float* gwb     = (float*)(ws + off); off += NROWS * 4;
    int*   cnt     = (int*)(ws + off);   off += 16 * 4;
    int*   offs    = (int*)(ws + off);   off += 16 * 4;
    int*   cursor  = (int*)(ws + off);   off += 16 * 4;
    int*   tile_e  = (int*)(ws + off);   off += MAXT2 * 4;
    int*   tile_row= (int*)(ws + off);   off += MAXT2 * 4;
    int*   ntiles  = (int*)(ws + off);   off += 16 * 4;
    (void)ws_size; (void)in_sizes; (void)n_in; (void)out_size;

    // allow >64KB dynamic LDS (idempotent; harmless if redundant)
    hipFuncSetAttribute((const void*)moe_gemm<1>,
                        hipFuncAttributeMaxDynamicSharedMemorySize, 131072);
    hipFuncSetAttribute((const void*)moe_gemm<2>,
                        hipFuncAttributeMaxDynamicSharedMemorySize, 98304);

    hipMemsetAsync(d_out, 0, (size_t)NB * ND * sizeof(float), stream);
    hipMemsetAsync(cnt, 0, 16 * 4, stream);

    k_route_count<<<dim3((NB + 255) / 256), 256, 0, stream>>>(idx, cnt);
    k_route_scan<<<1, 64, 0, stream>>>(cnt, offs, cursor, tile_e, tile_row, ntiles);
    k_route_fill<<<dim3((NB + 255) / 256), 256, 0, stream>>>(idx, hw, cursor, tok, gwb);
    k_gather_cvt<<<dim3(NROWS), 256, 0, stream>>>(x, tok, Ag);
    k_transpose_cvt<<<dim3(NH / 64, ND / 64, NE), 256, 0, stream>>>(w1, w1t, ND, NH);
    k_transpose_cvt<<<dim3(ND / 64, NH / 64, NE), 256, 0, stream>>>(w2, w2t, NH, ND);

    moe_gemm<1><<<dim3(16 * MAXT2), 512, 131072, stream>>>(
        Ag, w1t, b1, h, nullptr, offs, tok, gwb, tile_e, tile_row, ntiles);
    moe_gemm<2><<<dim3(16 * MAXT2), 512, 98304, stream>>>(
        h, w2t, b2, nullptr, out, offs, tok, gwb, tile_e, tile_row, ntiles);
}